// Round 4
// baseline (626.139 us; speedup 1.0000x reference)
//
#include <hip/hip_runtime.h>
#include <hip/hip_bf16.h>

// LSS voxel pooling via inverted index (BEVPool-style), no float atomics.
//   x:    (B=8, N=6, D=41, H=16, W=44, C=64) f32
//   geom: (B, N, D, H, W, 3) f32
//   out:  (B, C=64, X=200, Y=200) f32
//
// bin = (b*200 + ix)*200 + iy,  kept iff 0<=ix<200, 0<=iy<200, iz==0
// (IEEE fp32 add + div + trunc-toward-zero matches reference .astype(int32))

#define NP        1385472
#define NP_PER_B  173184      // N*D*H*W
#define NXY       200
#define NBIN      320000      // 8*200*200
#define NBLK_SCAN 1250        // NBIN/256 exactly

// ---------------- phase A: bin each point + histogram ----------------
__global__ void bin_points(const float* __restrict__ geom,
                           int* __restrict__ bins,
                           int* __restrict__ counts) {
    int p = blockIdx.x * 256 + threadIdx.x;
    if (p >= NP) return;
    float gx = geom[(size_t)p * 3 + 0];
    float gy = geom[(size_t)p * 3 + 1];
    float gz = geom[(size_t)p * 3 + 2];
    int ix = (int)((gx + 50.0f) / 0.5f);
    int iy = (int)((gy + 50.0f) / 0.5f);
    int iz = (int)((gz + 10.0f) / 20.0f);
    int bin = -1;
    if (ix >= 0 && ix < NXY && iy >= 0 && iy < NXY && iz == 0) {
        int b = p / NP_PER_B;
        bin = (b * NXY + ix) * NXY + iy;
        atomicAdd(&counts[bin], 1);
    }
    bins[p] = bin;
}

// ---------------- phase B: exclusive scan of counts ----------------
__global__ void scan_blocks(const int* __restrict__ counts,
                            int* __restrict__ offsets,
                            int* __restrict__ blocksums) {
    __shared__ int tmp[256];
    int i = blockIdx.x * 256 + threadIdx.x;
    int v = (i < NBIN) ? counts[i] : 0;
    tmp[threadIdx.x] = v;
    __syncthreads();
    for (int d = 1; d < 256; d <<= 1) {
        int t = (threadIdx.x >= d) ? tmp[threadIdx.x - d] : 0;
        __syncthreads();
        tmp[threadIdx.x] += t;
        __syncthreads();
    }
    if (i < NBIN) offsets[i] = tmp[threadIdx.x] - v;   // exclusive
    if (threadIdx.x == 255) blocksums[blockIdx.x] = tmp[255];
}

__global__ void scan_sums(int* __restrict__ blocksums, int nblocks) {
    __shared__ int tmp[256];
    __shared__ int carry;
    if (threadIdx.x == 0) carry = 0;
    __syncthreads();
    for (int base = 0; base < nblocks; base += 256) {
        int i = base + threadIdx.x;
        int v = (i < nblocks) ? blocksums[i] : 0;
        tmp[threadIdx.x] = v;
        __syncthreads();
        for (int d = 1; d < 256; d <<= 1) {
            int t = (threadIdx.x >= d) ? tmp[threadIdx.x - d] : 0;
            __syncthreads();
            tmp[threadIdx.x] += t;
            __syncthreads();
        }
        if (i < nblocks) blocksums[i] = tmp[threadIdx.x] - v + carry;  // exclusive
        __syncthreads();
        if (threadIdx.x == 255) carry += tmp[255];
        __syncthreads();
    }
}

__global__ void add_block_offsets(int* __restrict__ offsets,
                                  const int* __restrict__ blocksums) {
    int i = blockIdx.x * 256 + threadIdx.x;
    if (i < NBIN) offsets[i] += blocksums[blockIdx.x];
}

// ---------------- phase C: scatter point indices into CSR ----------------
__global__ void scatter_idx(const int* __restrict__ bins,
                            const int* __restrict__ offsets,
                            int* __restrict__ cursor,
                            int* __restrict__ sorted) {
    int p = blockIdx.x * 256 + threadIdx.x;
    if (p >= NP) return;
    int bin = bins[p];
    if (bin >= 0) {
        int pos = atomicAdd(&cursor[bin], 1);
        sorted[offsets[bin] + pos] = p;
    }
}

// ---------------- phase D: gather + coalesced write ----------------
// block = one (b, ix) row = 200 bins; 4 waves, wave handles iy = w, w+4, ...
// lane = channel. Results staged in padded LDS tile then written coalesced.
__global__ __launch_bounds__(256) void gather(const float* __restrict__ x,
                                              const int* __restrict__ offsets,
                                              const int* __restrict__ counts,
                                              const int* __restrict__ sorted,
                                              float* __restrict__ out) {
    __shared__ float tile[64 * 201];   // [c][iy], pad 201 to kill bank conflicts
    const int bix  = blockIdx.x;       // b*200 + ix
    const int wave = threadIdx.x >> 6;
    const int lane = threadIdx.x & 63;

    for (int iy = wave; iy < NXY; iy += 4) {
        const int bin   = bix * NXY + iy;
        const int start = offsets[bin];
        const int len   = counts[bin];
        float acc = 0.0f;
        for (int k = 0; k < len; ++k) {
            const int pid = sorted[start + k];              // wave-uniform
            acc += x[(size_t)pid * 64 + lane];              // coalesced 256B
        }
        tile[lane * 201 + iy] = acc;
    }
    __syncthreads();

    const int b  = bix / NXY;
    const int ix = bix % NXY;
    float* obase = out + (size_t)b * 64 * 40000 + (size_t)ix * 200;
    for (int f = threadIdx.x; f < 64 * NXY; f += 256) {
        const int c  = f / NXY;
        const int iy = f % NXY;
        obase[(size_t)c * 40000 + iy] = tile[c * 201 + iy];
    }
}

// ---------------- fallback (round-1): direct atomic scatter ----------------
__global__ void lss_scatter_atomic(const float* __restrict__ x,
                                   const float* __restrict__ geom,
                                   float* __restrict__ out) {
    const int lane   = threadIdx.x & 63;
    const int wave   = (blockIdx.x * blockDim.x + threadIdx.x) >> 6;
    const int nwaves = (gridDim.x * blockDim.x) >> 6;
    for (int p = wave; p < NP; p += nwaves) {
        const float gx = geom[(size_t)p * 3 + 0];
        const float gy = geom[(size_t)p * 3 + 1];
        const float gz = geom[(size_t)p * 3 + 2];
        const int ix = (int)((gx + 50.0f) / 0.5f);
        const int iy = (int)((gy + 50.0f) / 0.5f);
        const int iz = (int)((gz + 10.0f) / 20.0f);
        if (ix >= 0 && ix < NXY && iy >= 0 && iy < NXY && iz == 0) {
            const int b = p / NP_PER_B;
            const float v = x[(size_t)p * 64 + lane];
            atomicAdd(&out[(((size_t)b * 64 + lane) * NXY + ix) * NXY + iy], v);
        }
    }
}

extern "C" void kernel_launch(void* const* d_in, const int* in_sizes, int n_in,
                              void* d_out, int out_size, void* d_ws, size_t ws_size,
                              hipStream_t stream) {
    const float* x    = (const float*)d_in[0];
    const float* geom = (const float*)d_in[1];
    float* out = (float*)d_out;

    // workspace carve-up
    char* ws = (char*)d_ws;
    size_t off = 0;
    int* counts    = (int*)(ws + off); off += (size_t)NBIN * 4;
    int* offsets   = (int*)(ws + off); off += (size_t)NBIN * 4;
    int* cursor    = (int*)(ws + off); off += (size_t)NBIN * 4;
    int* blocksums = (int*)(ws + off); off += (size_t)NBLK_SCAN * 4;
    int* bins      = (int*)(ws + off); off += (size_t)NP * 4;
    int* sorted    = (int*)(ws + off); off += (size_t)NP * 4;

    if (ws_size < off) {
        // fallback: direct atomic scatter
        hipMemsetAsync(out, 0, (size_t)out_size * sizeof(float), stream);
        lss_scatter_atomic<<<2048, 256, 0, stream>>>(x, geom, out);
        return;
    }

    hipMemsetAsync(counts, 0, (size_t)NBIN * 4, stream);
    hipMemsetAsync(cursor, 0, (size_t)NBIN * 4, stream);

    const int pblocks = (NP + 255) / 256;                 // 5412
    bin_points<<<pblocks, 256, 0, stream>>>(geom, bins, counts);
    scan_blocks<<<NBLK_SCAN, 256, 0, stream>>>(counts, offsets, blocksums);
    scan_sums<<<1, 256, 0, stream>>>(blocksums, NBLK_SCAN);
    add_block_offsets<<<NBLK_SCAN, 256, 0, stream>>>(offsets, blocksums);
    scatter_idx<<<pblocks, 256, 0, stream>>>(bins, offsets, cursor, sorted);
    gather<<<8 * NXY, 256, 0, stream>>>(x, offsets, counts, sorted, out);
}

// Round 5
// 565.827 us; speedup vs baseline: 1.1066x; 1.1066x over previous
//
#include <hip/hip_runtime.h>
#include <hip/hip_bf16.h>

// LSS voxel pooling via inverted index (BEVPool-style), no float global atomics.
//   x:    (B=8, N=6, D=41, H=16, W=44, C=64) f32
//   geom: (B, N, D, H, W, 3) f32
//   out:  (B, C=64, X=200, Y=200) f32
//
// bin = (b*200 + ix)*200 + iy,  kept iff 0<=ix<200, 0<=iy<200, iz==0
// (IEEE fp32 add + div + trunc-toward-zero matches reference .astype(int32))
//
// Phase D (gather) is point-parallel: sorted[] holds (pid<<8)|iy packed, a
// block owns one (b,ix) row's contiguous CSR segment, waves stream points
// 8-deep (8 independent 256B x loads in flight) and accumulate into a
// 64x201 LDS tile with ds_add_f32, then write out fully coalesced.

#define NP        1385472
#define NP_PER_B  173184      // N*D*H*W
#define NXY       200
#define NBIN      320000      // 8*200*200
#define NBLK_SCAN 1250        // NBIN/256 exactly
#define UNR       8           // outstanding x-loads per wave in gather

// ---------------- phase A: bin each point + histogram ----------------
__global__ void bin_points(const float* __restrict__ geom,
                           int* __restrict__ bins,
                           int* __restrict__ counts) {
    int p = blockIdx.x * 256 + threadIdx.x;
    if (p >= NP) return;
    float gx = geom[(size_t)p * 3 + 0];
    float gy = geom[(size_t)p * 3 + 1];
    float gz = geom[(size_t)p * 3 + 2];
    int ix = (int)((gx + 50.0f) / 0.5f);
    int iy = (int)((gy + 50.0f) / 0.5f);
    int iz = (int)((gz + 10.0f) / 20.0f);
    int bin = -1;
    if (ix >= 0 && ix < NXY && iy >= 0 && iy < NXY && iz == 0) {
        int b = p / NP_PER_B;
        bin = (b * NXY + ix) * NXY + iy;
        atomicAdd(&counts[bin], 1);
    }
    bins[p] = bin;
}

// ---------------- phase B: exclusive scan of counts ----------------
__global__ void scan_blocks(const int* __restrict__ counts,
                            int* __restrict__ offsets,
                            int* __restrict__ blocksums) {
    __shared__ int tmp[256];
    int i = blockIdx.x * 256 + threadIdx.x;
    int v = (i < NBIN) ? counts[i] : 0;
    tmp[threadIdx.x] = v;
    __syncthreads();
    for (int d = 1; d < 256; d <<= 1) {
        int t = (threadIdx.x >= d) ? tmp[threadIdx.x - d] : 0;
        __syncthreads();
        tmp[threadIdx.x] += t;
        __syncthreads();
    }
    if (i < NBIN) offsets[i] = tmp[threadIdx.x] - v;   // exclusive
    if (threadIdx.x == 255) blocksums[blockIdx.x] = tmp[255];
}

__global__ void scan_sums(int* __restrict__ blocksums, int nblocks) {
    __shared__ int tmp[256];
    __shared__ int carry;
    if (threadIdx.x == 0) carry = 0;
    __syncthreads();
    for (int base = 0; base < nblocks; base += 256) {
        int i = base + threadIdx.x;
        int v = (i < nblocks) ? blocksums[i] : 0;
        tmp[threadIdx.x] = v;
        __syncthreads();
        for (int d = 1; d < 256; d <<= 1) {
            int t = (threadIdx.x >= d) ? tmp[threadIdx.x - d] : 0;
            __syncthreads();
            tmp[threadIdx.x] += t;
            __syncthreads();
        }
        if (i < nblocks) blocksums[i] = tmp[threadIdx.x] - v + carry;  // exclusive
        __syncthreads();
        if (threadIdx.x == 255) carry += tmp[255];
        __syncthreads();
    }
}

__global__ void add_block_offsets(int* __restrict__ offsets,
                                  const int* __restrict__ blocksums) {
    int i = blockIdx.x * 256 + threadIdx.x;
    if (i < NBIN) offsets[i] += blocksums[blockIdx.x];
}

// ---------------- phase C: scatter packed (pid,iy) into CSR ----------------
__global__ void scatter_idx(const int* __restrict__ bins,
                            const int* __restrict__ offsets,
                            int* __restrict__ cursor,
                            unsigned int* __restrict__ sorted) {
    int p = blockIdx.x * 256 + threadIdx.x;
    if (p >= NP) return;
    int bin = bins[p];
    if (bin >= 0) {
        int pos = atomicAdd(&cursor[bin], 1);
        sorted[offsets[bin] + pos] = ((unsigned int)p << 8) | (unsigned int)(bin % NXY);
    }
}

// ---------------- phase D: point-parallel gather, 8-deep MLP ----------------
__global__ __launch_bounds__(256) void gather2(const float* __restrict__ x,
                                               const int* __restrict__ offsets,
                                               const int* __restrict__ counts,
                                               const unsigned int* __restrict__ packed,
                                               float* __restrict__ out) {
    __shared__ float tile[64 * 201];   // [c][iy], 201: 2-way bank alias only
    for (int f = threadIdx.x; f < 64 * 201; f += 256) tile[f] = 0.0f;
    __syncthreads();

    const int bix  = blockIdx.x;       // b*200 + ix
    const int wave = threadIdx.x >> 6;
    const int lane = threadIdx.x & 63;

    // contiguous CSR segment of this row (bins bix*200 .. bix*200+199)
    const int rs = offsets[bix * NXY];
    const int re = offsets[bix * NXY + NXY - 1] + counts[bix * NXY + NXY - 1];

    for (int base = rs + wave * UNR; base < re; base += 4 * UNR) {
        unsigned int pk[UNR];
#pragma unroll
        for (int u = 0; u < UNR; ++u)
            pk[u] = (base + u < re) ? packed[base + u] : 0xFFFFFFFFu;  // independent
        float v[UNR];
#pragma unroll
        for (int u = 0; u < UNR; ++u)
            if (pk[u] != 0xFFFFFFFFu)
                v[u] = x[(size_t)(pk[u] >> 8) * 64 + lane];            // 8 x 256B in flight
#pragma unroll
        for (int u = 0; u < UNR; ++u)
            if (pk[u] != 0xFFFFFFFFu)
                atomicAdd(&tile[lane * 201 + (int)(pk[u] & 0xFFu)], v[u]);  // ds_add_f32
    }
    __syncthreads();

    const int b  = bix / NXY;
    const int ix = bix % NXY;
    float* obase = out + (size_t)b * 64 * 40000 + (size_t)ix * 200;
    for (int f = threadIdx.x; f < 64 * NXY; f += 256) {
        const int c  = f / NXY;
        const int iy = f % NXY;
        obase[(size_t)c * 40000 + iy] = tile[c * 201 + iy];
    }
}

// ---------------- fallback (round-1): direct atomic scatter ----------------
__global__ void lss_scatter_atomic(const float* __restrict__ x,
                                   const float* __restrict__ geom,
                                   float* __restrict__ out) {
    const int lane   = threadIdx.x & 63;
    const int wave   = (blockIdx.x * blockDim.x + threadIdx.x) >> 6;
    const int nwaves = (gridDim.x * blockDim.x) >> 6;
    for (int p = wave; p < NP; p += nwaves) {
        const float gx = geom[(size_t)p * 3 + 0];
        const float gy = geom[(size_t)p * 3 + 1];
        const float gz = geom[(size_t)p * 3 + 2];
        const int ix = (int)((gx + 50.0f) / 0.5f);
        const int iy = (int)((gy + 50.0f) / 0.5f);
        const int iz = (int)((gz + 10.0f) / 20.0f);
        if (ix >= 0 && ix < NXY && iy >= 0 && iy < NXY && iz == 0) {
            const int b = p / NP_PER_B;
            const float v = x[(size_t)p * 64 + lane];
            atomicAdd(&out[(((size_t)b * 64 + lane) * NXY + ix) * NXY + iy], v);
        }
    }
}

extern "C" void kernel_launch(void* const* d_in, const int* in_sizes, int n_in,
                              void* d_out, int out_size, void* d_ws, size_t ws_size,
                              hipStream_t stream) {
    const float* x    = (const float*)d_in[0];
    const float* geom = (const float*)d_in[1];
    float* out = (float*)d_out;

    // workspace carve-up
    char* ws = (char*)d_ws;
    size_t off = 0;
    int* counts    = (int*)(ws + off); off += (size_t)NBIN * 4;
    int* offsets   = (int*)(ws + off); off += (size_t)NBIN * 4;
    int* cursor    = (int*)(ws + off); off += (size_t)NBIN * 4;
    int* blocksums = (int*)(ws + off); off += (size_t)NBLK_SCAN * 4;
    int* bins      = (int*)(ws + off); off += (size_t)NP * 4;
    unsigned int* sorted = (unsigned int*)(ws + off); off += (size_t)NP * 4;

    if (ws_size < off) {
        // fallback: direct atomic scatter
        hipMemsetAsync(out, 0, (size_t)out_size * sizeof(float), stream);
        lss_scatter_atomic<<<2048, 256, 0, stream>>>(x, geom, out);
        return;
    }

    hipMemsetAsync(counts, 0, (size_t)NBIN * 4, stream);
    hipMemsetAsync(cursor, 0, (size_t)NBIN * 4, stream);

    const int pblocks = (NP + 255) / 256;                 // 5412
    bin_points<<<pblocks, 256, 0, stream>>>(geom, bins, counts);
    scan_blocks<<<NBLK_SCAN, 256, 0, stream>>>(counts, offsets, blocksums);
    scan_sums<<<1, 256, 0, stream>>>(blocksums, NBLK_SCAN);
    add_block_offsets<<<NBLK_SCAN, 256, 0, stream>>>(offsets, blocksums);
    scatter_idx<<<pblocks, 256, 0, stream>>>(bins, offsets, cursor, sorted);
    gather2<<<8 * NXY, 256, 0, stream>>>(x, offsets, counts, sorted, out);
}

// Round 6
// 522.575 us; speedup vs baseline: 1.1982x; 1.0828x over previous
//
#include <hip/hip_runtime.h>
#include <hip/hip_bf16.h>

// LSS voxel pooling via inverted index (BEVPool-style), no float global atomics.
//   x:    (B=8, N=6, D=41, H=16, W=44, C=64) f32
//   geom: (B, N, D, H, W, 3) f32
//   out:  (B, C=64, X=200, Y=200) f32
//
// bin = (b*200 + ix)*200 + iy,  kept iff 0<=ix<200, 0<=iy<200, iz==0
// (IEEE fp32 add + div + trunc-toward-zero matches reference .astype(int32))
//
// Phase D (gather3): block = half a (b,ix) row (100 bins, contiguous CSR
// segment). Main loop is BRANCH-FREE groups of 8: issue 8 wave-uniform pk
// loads, 8 independent 256B x-row loads, 8 ds_add_f32 into a 64x101 LDS
// tile; next pk batch issued while x loads are in flight. <=7-point tail
// handled by a tiny guarded loop. 25.9KB LDS -> 6 blocks/CU (24 waves).

#define NP        1385472
#define NP_PER_B  173184      // N*D*H*W
#define NXY       200
#define NBIN      320000      // 8*200*200
#define NBLK_SCAN 1250        // NBIN/256 exactly
#define UNR       8           // outstanding x-loads per wave in gather

// ---------------- phase A: bin each point + histogram ----------------
__global__ void bin_points(const float* __restrict__ geom,
                           int* __restrict__ bins,
                           int* __restrict__ counts) {
    int p = blockIdx.x * 256 + threadIdx.x;
    if (p >= NP) return;
    float gx = geom[(size_t)p * 3 + 0];
    float gy = geom[(size_t)p * 3 + 1];
    float gz = geom[(size_t)p * 3 + 2];
    int ix = (int)((gx + 50.0f) / 0.5f);
    int iy = (int)((gy + 50.0f) / 0.5f);
    int iz = (int)((gz + 10.0f) / 20.0f);
    int bin = -1;
    if (ix >= 0 && ix < NXY && iy >= 0 && iy < NXY && iz == 0) {
        int b = p / NP_PER_B;
        bin = (b * NXY + ix) * NXY + iy;
        atomicAdd(&counts[bin], 1);
    }
    bins[p] = bin;
}

// ---------------- phase B: exclusive scan of counts ----------------
__global__ void scan_blocks(const int* __restrict__ counts,
                            int* __restrict__ offsets,
                            int* __restrict__ blocksums) {
    __shared__ int tmp[256];
    int i = blockIdx.x * 256 + threadIdx.x;
    int v = (i < NBIN) ? counts[i] : 0;
    tmp[threadIdx.x] = v;
    __syncthreads();
    for (int d = 1; d < 256; d <<= 1) {
        int t = (threadIdx.x >= d) ? tmp[threadIdx.x - d] : 0;
        __syncthreads();
        tmp[threadIdx.x] += t;
        __syncthreads();
    }
    if (i < NBIN) offsets[i] = tmp[threadIdx.x] - v;   // exclusive
    if (threadIdx.x == 255) blocksums[blockIdx.x] = tmp[255];
}

__global__ void scan_sums(int* __restrict__ blocksums, int nblocks) {
    __shared__ int tmp[256];
    __shared__ int carry;
    if (threadIdx.x == 0) carry = 0;
    __syncthreads();
    for (int base = 0; base < nblocks; base += 256) {
        int i = base + threadIdx.x;
        int v = (i < nblocks) ? blocksums[i] : 0;
        tmp[threadIdx.x] = v;
        __syncthreads();
        for (int d = 1; d < 256; d <<= 1) {
            int t = (threadIdx.x >= d) ? tmp[threadIdx.x - d] : 0;
            __syncthreads();
            tmp[threadIdx.x] += t;
            __syncthreads();
        }
        if (i < nblocks) blocksums[i] = tmp[threadIdx.x] - v + carry;  // exclusive
        __syncthreads();
        if (threadIdx.x == 255) carry += tmp[255];
        __syncthreads();
    }
}

__global__ void add_block_offsets(int* __restrict__ offsets,
                                  const int* __restrict__ blocksums) {
    int i = blockIdx.x * 256 + threadIdx.x;
    if (i < NBIN) offsets[i] += blocksums[blockIdx.x];
}

// ---------------- phase C: scatter packed (pid,iy) into CSR ----------------
__global__ void scatter_idx(const int* __restrict__ bins,
                            const int* __restrict__ offsets,
                            int* __restrict__ cursor,
                            unsigned int* __restrict__ sorted) {
    int p = blockIdx.x * 256 + threadIdx.x;
    if (p >= NP) return;
    int bin = bins[p];
    if (bin >= 0) {
        int pos = atomicAdd(&cursor[bin], 1);
        sorted[offsets[bin] + pos] = ((unsigned int)p << 8) | (unsigned int)(bin % NXY);
    }
}

// ---------------- phase D: branch-free 8-deep point-parallel gather ----------
__global__ __launch_bounds__(256, 6) void gather3(const float* __restrict__ x,
                                                  const int* __restrict__ offsets,
                                                  const int* __restrict__ counts,
                                                  const unsigned int* __restrict__ packed,
                                                  float* __restrict__ out) {
    __shared__ float tile[64 * 101];   // [c][iy_local], 101: 2-way bank alias only
    for (int f = threadIdx.x; f < 64 * 101; f += 256) tile[f] = 0.0f;
    __syncthreads();

    const int bix   = blockIdx.x >> 1;        // b*200 + ix
    const int half  = blockIdx.x & 1;         // iy half: 0 -> 0..99, 1 -> 100..199
    const int hbase = half * 100;
    const int wave  = threadIdx.x >> 6;
    const int lane  = threadIdx.x & 63;

    // contiguous CSR segment of this half-row (100 consecutive bins)
    const int bin0 = bix * NXY + hbase;
    const int rs = offsets[bin0];
    const int re = offsets[bin0 + 99] + counts[bin0 + 99];

    const int stride = 4 * UNR;
    int base = rs + wave * UNR;

    unsigned int pk[UNR];
    bool have = (base + UNR <= re);
    if (have) {
#pragma unroll
        for (int u = 0; u < UNR; ++u) pk[u] = packed[base + u];
    }
    while (have) {
        // 8 independent 256B x-row loads (no guards -> stay in flight together)
        float v[UNR];
#pragma unroll
        for (int u = 0; u < UNR; ++u)
            v[u] = x[(size_t)(pk[u] >> 8) * 64 + lane];

        // software-pipeline: issue next pk batch while x loads are in flight
        const int nbase = base + stride;
        const bool have2 = (nbase + UNR <= re);
        unsigned int pk2[UNR];
        if (have2) {
#pragma unroll
            for (int u = 0; u < UNR; ++u) pk2[u] = packed[nbase + u];
        }

#pragma unroll
        for (int u = 0; u < UNR; ++u)
            atomicAdd(&tile[lane * 101 + (int)(pk[u] & 0xFFu) - hbase], v[u]);  // ds_add_f32

#pragma unroll
        for (int u = 0; u < UNR; ++u) pk[u] = pk2[u];
        base = nbase;
        have = have2;
    }
    // tail: each wave's first unprocessed group; only the wave whose group
    // straddles re does work here (<= 7 points)
    for (int i = base; i < re; ++i) {
        const unsigned int p = packed[i];
        const float vv = x[(size_t)(p >> 8) * 64 + lane];
        atomicAdd(&tile[lane * 101 + (int)(p & 0xFFu) - hbase], vv);
    }
    __syncthreads();

    const int b  = bix / NXY;
    const int ix = bix % NXY;
    float* obase = out + (size_t)b * 64 * 40000 + (size_t)ix * 200 + hbase;
    for (int f = threadIdx.x; f < 64 * 100; f += 256) {
        const int c  = f / 100;
        const int iy = f % 100;
        obase[(size_t)c * 40000 + iy] = tile[c * 101 + iy];
    }
}

// ---------------- fallback (round-1): direct atomic scatter ----------------
__global__ void lss_scatter_atomic(const float* __restrict__ x,
                                   const float* __restrict__ geom,
                                   float* __restrict__ out) {
    const int lane   = threadIdx.x & 63;
    const int wave   = (blockIdx.x * blockDim.x + threadIdx.x) >> 6;
    const int nwaves = (gridDim.x * blockDim.x) >> 6;
    for (int p = wave; p < NP; p += nwaves) {
        const float gx = geom[(size_t)p * 3 + 0];
        const float gy = geom[(size_t)p * 3 + 1];
        const float gz = geom[(size_t)p * 3 + 2];
        const int ix = (int)((gx + 50.0f) / 0.5f);
        const int iy = (int)((gy + 50.0f) / 0.5f);
        const int iz = (int)((gz + 10.0f) / 20.0f);
        if (ix >= 0 && ix < NXY && iy >= 0 && iy < NXY && iz == 0) {
            const int b = p / NP_PER_B;
            const float v = x[(size_t)p * 64 + lane];
            atomicAdd(&out[(((size_t)b * 64 + lane) * NXY + ix) * NXY + iy], v);
        }
    }
}

extern "C" void kernel_launch(void* const* d_in, const int* in_sizes, int n_in,
                              void* d_out, int out_size, void* d_ws, size_t ws_size,
                              hipStream_t stream) {
    const float* x    = (const float*)d_in[0];
    const float* geom = (const float*)d_in[1];
    float* out = (float*)d_out;

    // workspace carve-up
    char* ws = (char*)d_ws;
    size_t off = 0;
    int* counts    = (int*)(ws + off); off += (size_t)NBIN * 4;
    int* offsets   = (int*)(ws + off); off += (size_t)NBIN * 4;
    int* cursor    = (int*)(ws + off); off += (size_t)NBIN * 4;
    int* blocksums = (int*)(ws + off); off += (size_t)NBLK_SCAN * 4;
    int* bins      = (int*)(ws + off); off += (size_t)NP * 4;
    unsigned int* sorted = (unsigned int*)(ws + off); off += (size_t)NP * 4;

    if (ws_size < off) {
        // fallback: direct atomic scatter
        hipMemsetAsync(out, 0, (size_t)out_size * sizeof(float), stream);
        lss_scatter_atomic<<<2048, 256, 0, stream>>>(x, geom, out);
        return;
    }

    hipMemsetAsync(counts, 0, (size_t)NBIN * 4, stream);
    hipMemsetAsync(cursor, 0, (size_t)NBIN * 4, stream);

    const int pblocks = (NP + 255) / 256;                 // 5412
    bin_points<<<pblocks, 256, 0, stream>>>(geom, bins, counts);
    scan_blocks<<<NBLK_SCAN, 256, 0, stream>>>(counts, offsets, blocksums);
    scan_sums<<<1, 256, 0, stream>>>(blocksums, NBLK_SCAN);
    add_block_offsets<<<NBLK_SCAN, 256, 0, stream>>>(offsets, blocksums);
    scatter_idx<<<pblocks, 256, 0, stream>>>(bins, offsets, cursor, sorted);
    gather3<<<2 * 8 * NXY, 256, 0, stream>>>(x, offsets, counts, sorted, out);
}

// Round 7
// 205.615 us; speedup vs baseline: 3.0452x; 2.5415x over previous
//
#include <hip/hip_runtime.h>
#include <hip/hip_bf16.h>

// LSS voxel pooling via inverted index (BEVPool-style), no atomics in gather.
//   x:    (B=8, N=6, D=41, H=16, W=44, C=64) f32
//   geom: (B, N, D, H, W, 3) f32
//   out:  (B, C=64, X=200, Y=200) f32
//
// bin = (b*200 + ix)*200 + iy,  kept iff 0<=ix<200, 0<=iy<200, iz==0
// (IEEE fp32 add + div + trunc-toward-zero matches reference .astype(int32))
//
// Phase D (gather4): block = half a (b,ix) row (100 bins). Each wave owns an
// EXCLUSIVE 25-bin sub-segment (contiguous CSR range, points sorted by bin),
// streams points 8-deep with nontemporal 256B x loads, accumulates the
// current bin in a REGISTER (bin-change is a wave-uniform scalar branch),
// and flushes one plain ds_write per non-empty bin. Zero LDS/global atomics.

#define NP        1385472
#define NP_PER_B  173184      // N*D*H*W
#define NXY       200
#define NBIN      320000      // 8*200*200
#define NBLK_SCAN 1250        // NBIN/256 exactly
#define UNR       8           // outstanding x-loads per wave in gather
#define BINS_PER_WAVE 25      // 100 bins per block / 4 waves

// ---------------- phase A: bin each point + histogram ----------------
__global__ void bin_points(const float* __restrict__ geom,
                           int* __restrict__ bins,
                           int* __restrict__ counts) {
    int p = blockIdx.x * 256 + threadIdx.x;
    if (p >= NP) return;
    float gx = geom[(size_t)p * 3 + 0];
    float gy = geom[(size_t)p * 3 + 1];
    float gz = geom[(size_t)p * 3 + 2];
    int ix = (int)((gx + 50.0f) / 0.5f);
    int iy = (int)((gy + 50.0f) / 0.5f);
    int iz = (int)((gz + 10.0f) / 20.0f);
    int bin = -1;
    if (ix >= 0 && ix < NXY && iy >= 0 && iy < NXY && iz == 0) {
        int b = p / NP_PER_B;
        bin = (b * NXY + ix) * NXY + iy;
        atomicAdd(&counts[bin], 1);
    }
    bins[p] = bin;
}

// ---------------- phase B: exclusive scan of counts ----------------
__global__ void scan_blocks(const int* __restrict__ counts,
                            int* __restrict__ offsets,
                            int* __restrict__ blocksums) {
    __shared__ int tmp[256];
    int i = blockIdx.x * 256 + threadIdx.x;
    int v = (i < NBIN) ? counts[i] : 0;
    tmp[threadIdx.x] = v;
    __syncthreads();
    for (int d = 1; d < 256; d <<= 1) {
        int t = (threadIdx.x >= d) ? tmp[threadIdx.x - d] : 0;
        __syncthreads();
        tmp[threadIdx.x] += t;
        __syncthreads();
    }
    if (i < NBIN) offsets[i] = tmp[threadIdx.x] - v;   // exclusive
    if (threadIdx.x == 255) blocksums[blockIdx.x] = tmp[255];
}

__global__ void scan_sums(int* __restrict__ blocksums, int nblocks) {
    __shared__ int tmp[256];
    __shared__ int carry;
    if (threadIdx.x == 0) carry = 0;
    __syncthreads();
    for (int base = 0; base < nblocks; base += 256) {
        int i = base + threadIdx.x;
        int v = (i < nblocks) ? blocksums[i] : 0;
        tmp[threadIdx.x] = v;
        __syncthreads();
        for (int d = 1; d < 256; d <<= 1) {
            int t = (threadIdx.x >= d) ? tmp[threadIdx.x - d] : 0;
            __syncthreads();
            tmp[threadIdx.x] += t;
            __syncthreads();
        }
        if (i < nblocks) blocksums[i] = tmp[threadIdx.x] - v + carry;  // exclusive
        __syncthreads();
        if (threadIdx.x == 255) carry += tmp[255];
        __syncthreads();
    }
}

__global__ void add_block_offsets(int* __restrict__ offsets,
                                  const int* __restrict__ blocksums) {
    int i = blockIdx.x * 256 + threadIdx.x;
    if (i < NBIN) offsets[i] += blocksums[blockIdx.x];
}

// ---------------- phase C: scatter packed (pid,iy) into CSR ----------------
__global__ void scatter_idx(const int* __restrict__ bins,
                            const int* __restrict__ offsets,
                            int* __restrict__ cursor,
                            unsigned int* __restrict__ sorted) {
    int p = blockIdx.x * 256 + threadIdx.x;
    if (p >= NP) return;
    int bin = bins[p];
    if (bin >= 0) {
        int pos = atomicAdd(&cursor[bin], 1);
        sorted[offsets[bin] + pos] = ((unsigned int)p << 8) | (unsigned int)(bin % NXY);
    }
}

// ------- phase D: atomic-free gather, register accumulation per bin -------
__global__ __launch_bounds__(256, 6) void gather4(const float* __restrict__ x,
                                                  const int* __restrict__ offsets,
                                                  const int* __restrict__ counts,
                                                  const unsigned int* __restrict__ packed,
                                                  float* __restrict__ out) {
    __shared__ float tile[64 * 101];   // [c][iy_local], 101: 2-way bank alias only
    for (int f = threadIdx.x; f < 64 * 101; f += 256) tile[f] = 0.0f;
    __syncthreads();

    const int bix   = blockIdx.x >> 1;        // b*200 + ix
    const int half  = blockIdx.x & 1;         // iy half: 0 -> 0..99, 1 -> 100..199
    const int hbase = half * 100;
    const int wave  = threadIdx.x >> 6;
    const int lane  = threadIdx.x & 63;

    // wave-exclusive contiguous CSR range: bins [bin0, bin0+25)
    const int bin0 = bix * NXY + hbase + wave * BINS_PER_WAVE;
    const int ps = offsets[bin0];
    const int pe = offsets[bin0 + BINS_PER_WAVE - 1] + counts[bin0 + BINS_PER_WAVE - 1];

    int   cur = -1;       // current global iy being accumulated (wave-uniform)
    float acc = 0.0f;     // per-lane accumulator for channel `lane` of bin cur

    int i = ps;
    unsigned int pk[UNR];
    bool have = (i + UNR <= pe);
    if (have) {
#pragma unroll
        for (int u = 0; u < UNR; ++u) pk[u] = packed[i + u];
    }
    while (have) {
        // 8 independent nontemporal 256B x-row loads (no L1 allocate)
        float v[UNR];
#pragma unroll
        for (int u = 0; u < UNR; ++u)
            v[u] = __builtin_nontemporal_load(&x[(size_t)(pk[u] >> 8) * 64 + lane]);

        // software-pipeline next pk batch while x loads are in flight
        const int ni = i + UNR;
        const bool have2 = (ni + UNR <= pe);
        unsigned int pk2[UNR];
        if (have2) {
#pragma unroll
            for (int u = 0; u < UNR; ++u) pk2[u] = packed[ni + u];
        }

        // register accumulation; bin-change is wave-uniform (scalar branch)
#pragma unroll
        for (int u = 0; u < UNR; ++u) {
            const int iy = (int)(__builtin_amdgcn_readfirstlane(pk[u]) & 0xFFu);
            if (iy != cur) {
                if (cur >= 0) tile[lane * 101 + (cur - hbase)] = acc;  // plain ds_write
                cur = iy;
                acc = v[u];
            } else {
                acc += v[u];
            }
        }

#pragma unroll
        for (int u = 0; u < UNR; ++u) pk[u] = pk2[u];
        i = ni;
        have = have2;
    }
    // tail (< 8 points)
    for (; i < pe; ++i) {
        const unsigned int p = packed[i];
        const float vv = __builtin_nontemporal_load(&x[(size_t)(p >> 8) * 64 + lane]);
        const int iy = (int)(__builtin_amdgcn_readfirstlane(p) & 0xFFu);
        if (iy != cur) {
            if (cur >= 0) tile[lane * 101 + (cur - hbase)] = acc;
            cur = iy;
            acc = vv;
        } else {
            acc += vv;
        }
    }
    if (cur >= 0) tile[lane * 101 + (cur - hbase)] = acc;  // final flush
    __syncthreads();

    const int b  = bix / NXY;
    const int ix = bix % NXY;
    float* obase = out + (size_t)b * 64 * 40000 + (size_t)ix * 200 + hbase;
    for (int f = threadIdx.x; f < 64 * 100; f += 256) {
        const int c  = f / 100;
        const int iy = f % 100;
        obase[(size_t)c * 40000 + iy] = tile[c * 101 + iy];
    }
}

// ---------------- fallback (round-1): direct atomic scatter ----------------
__global__ void lss_scatter_atomic(const float* __restrict__ x,
                                   const float* __restrict__ geom,
                                   float* __restrict__ out) {
    const int lane   = threadIdx.x & 63;
    const int wave   = (blockIdx.x * blockDim.x + threadIdx.x) >> 6;
    const int nwaves = (gridDim.x * blockDim.x) >> 6;
    for (int p = wave; p < NP; p += nwaves) {
        const float gx = geom[(size_t)p * 3 + 0];
        const float gy = geom[(size_t)p * 3 + 1];
        const float gz = geom[(size_t)p * 3 + 2];
        const int ix = (int)((gx + 50.0f) / 0.5f);
        const int iy = (int)((gy + 50.0f) / 0.5f);
        const int iz = (int)((gz + 10.0f) / 20.0f);
        if (ix >= 0 && ix < NXY && iy >= 0 && iy < NXY && iz == 0) {
            const int b = p / NP_PER_B;
            const float v = x[(size_t)p * 64 + lane];
            atomicAdd(&out[(((size_t)b * 64 + lane) * NXY + ix) * NXY + iy], v);
        }
    }
}

extern "C" void kernel_launch(void* const* d_in, const int* in_sizes, int n_in,
                              void* d_out, int out_size, void* d_ws, size_t ws_size,
                              hipStream_t stream) {
    const float* x    = (const float*)d_in[0];
    const float* geom = (const float*)d_in[1];
    float* out = (float*)d_out;

    // workspace carve-up
    char* ws = (char*)d_ws;
    size_t off = 0;
    int* counts    = (int*)(ws + off); off += (size_t)NBIN * 4;
    int* offsets   = (int*)(ws + off); off += (size_t)NBIN * 4;
    int* cursor    = (int*)(ws + off); off += (size_t)NBIN * 4;
    int* blocksums = (int*)(ws + off); off += (size_t)NBLK_SCAN * 4;
    int* bins      = (int*)(ws + off); off += (size_t)NP * 4;
    unsigned int* sorted = (unsigned int*)(ws + off); off += (size_t)NP * 4;

    if (ws_size < off) {
        // fallback: direct atomic scatter
        hipMemsetAsync(out, 0, (size_t)out_size * sizeof(float), stream);
        lss_scatter_atomic<<<2048, 256, 0, stream>>>(x, geom, out);
        return;
    }

    hipMemsetAsync(counts, 0, (size_t)NBIN * 4, stream);
    hipMemsetAsync(cursor, 0, (size_t)NBIN * 4, stream);

    const int pblocks = (NP + 255) / 256;                 // 5412
    bin_points<<<pblocks, 256, 0, stream>>>(geom, bins, counts);
    scan_blocks<<<NBLK_SCAN, 256, 0, stream>>>(counts, offsets, blocksums);
    scan_sums<<<1, 256, 0, stream>>>(blocksums, NBLK_SCAN);
    add_block_offsets<<<NBLK_SCAN, 256, 0, stream>>>(offsets, blocksums);
    scatter_idx<<<pblocks, 256, 0, stream>>>(bins, offsets, cursor, sorted);
    gather4<<<2 * 8 * NXY, 256, 0, stream>>>(x, offsets, counts, sorted, out);
}